// Round 1
// baseline (917.424 us; speedup 1.0000x reference)
//
#include <hip/hip_runtime.h>
#include <math.h>

// Problem constants (from reference)
#define T_TOK 8192
#define D_DIM 7168
#define E_EXP 256
#define K_SEL 8
#define G_GRP 8
#define LG_GRP 4
#define ROUTE_SCALE 2.5f

// ---------------- GEMM: logits[T,E] = x[T,D] @ W[E,D]^T (fp32) ----------------
// BM=BN=64, BK=64, 256 threads (16x16), each thread computes a 4x4 micro-tile.
// LDS tiles stored transposed [k][m] with +4 pad (stride 68 floats = 272 B:
// keeps float4 alignment; 68 mod 32 = 4 banks shift per row; micro-tile b128
// reads are broadcast (A) / 2-way (B) -> conflict-free per m136).
#define BM 64
#define BN 64
#define BK 64
#define LPAD 4

__global__ __launch_bounds__(256, 2)
void gemm_logits_kernel(const float* __restrict__ x,
                        const float* __restrict__ W,
                        float* __restrict__ logits) {
    __shared__ __align__(16) float As[BK][BM + LPAD];
    __shared__ __align__(16) float Bs[BK][BN + LPAD];

    const int bid = blockIdx.x;          // 512 blocks
    const int be  = bid & 3;             // expert tile fastest: 4 blocks sharing
    const int bm  = bid >> 2;            // an x-tile are adjacent in dispatch
    const int tid = threadIdx.x;
    const int tx  = tid & 15;            // expert dir
    const int ty  = tid >> 4;            // token dir

    const int row0 = bm * BM;
    const int col0 = be * BN;

    const float* __restrict__ xA = x + (size_t)row0 * D_DIM;
    const float* __restrict__ wB = W + (size_t)col0 * D_DIM;

    float acc[4][4] = {};

    for (int k0 = 0; k0 < D_DIM; k0 += BK) {
        // Stage A and B tiles: 64 rows x 64 k each = 1024 float4 / tile,
        // 256 threads -> 4 float4 per thread per tile. Fully coalesced
        // (16 threads cover one 256 B row segment).
        #pragma unroll
        for (int i = 0; i < 4; i++) {
            const int idx = tid + i * 256;   // 0..1023
            const int r   = idx >> 4;        // 0..63 (row within tile)
            const int c4  = (idx & 15) * 4;  // 0..60 (k offset)
            float4 a = *(const float4*)(xA + (size_t)r * D_DIM + k0 + c4);
            As[c4 + 0][r] = a.x; As[c4 + 1][r] = a.y;
            As[c4 + 2][r] = a.z; As[c4 + 3][r] = a.w;
            float4 b = *(const float4*)(wB + (size_t)r * D_DIM + k0 + c4);
            Bs[c4 + 0][r] = b.x; Bs[c4 + 1][r] = b.y;
            Bs[c4 + 2][r] = b.z; Bs[c4 + 3][r] = b.w;
        }
        __syncthreads();

        #pragma unroll 16
        for (int k = 0; k < BK; k++) {
            const float4 av = *(const float4*)&As[k][ty * 4];
            const float4 bv = *(const float4*)&Bs[k][tx * 4];
            const float a[4] = {av.x, av.y, av.z, av.w};
            const float b[4] = {bv.x, bv.y, bv.z, bv.w};
            #pragma unroll
            for (int i = 0; i < 4; i++)
                #pragma unroll
                for (int j = 0; j < 4; j++)
                    acc[i][j] = fmaf(a[i], b[j], acc[i][j]);
        }
        __syncthreads();
    }

    #pragma unroll
    for (int i = 0; i < 4; i++) {
        float4 v = make_float4(acc[i][0], acc[i][1], acc[i][2], acc[i][3]);
        *(float4*)(logits + (size_t)(row0 + ty * 4 + i) * E_EXP + col0 + tx * 4) = v;
    }
}

// ---------------- zero the counts region of d_out ----------------
__global__ void zero_counts_kernel(float* __restrict__ c) {
    c[threadIdx.x] = 0.0f;
}

// ---------------- routing: one wave (64 lanes) per token ----------------
// lane l owns experts 4l..4l+3 (one float4). Group g = lanes [8g, 8g+7].
__global__ __launch_bounds__(256)
void routing_kernel(const float* __restrict__ logits,
                    const float* __restrict__ bias,
                    float* __restrict__ out_w,   // [T,K] weights (fp32)
                    float* __restrict__ out_i,   // [T,K] indices as float
                    float* __restrict__ out_c) { // [E]   counts as float
    const int wave = threadIdx.x >> 6;
    const int lane = threadIdx.x & 63;
    const int t    = blockIdx.x * 4 + wave;

    const float4 lg = *(const float4*)(logits + (size_t)t * E_EXP + lane * 4);
    const float4 bi = *(const float4*)(bias + lane * 4);

    float orig[4], s[4];
    orig[0] = 1.0f / (1.0f + expf(-lg.x));
    orig[1] = 1.0f / (1.0f + expf(-lg.y));
    orig[2] = 1.0f / (1.0f + expf(-lg.z));
    orig[3] = 1.0f / (1.0f + expf(-lg.w));
    s[0] = orig[0] + bi.x;
    s[1] = orig[1] + bi.y;
    s[2] = orig[2] + bi.z;
    s[3] = orig[3] + bi.w;

    // ---- per-lane top-2 of its 4 scores ----
    float p1 = fmaxf(s[0], s[1]), p2 = fminf(s[0], s[1]);
    float q1 = fmaxf(s[2], s[3]), q2 = fminf(s[2], s[3]);
    float m1 = fmaxf(p1, q1);
    float m2 = fmaxf(fminf(p1, q1), (p1 >= q1) ? p2 : q2);

    // ---- merge sorted pairs across the 8 lanes of the group ----
    #pragma unroll
    for (int off = 1; off <= 4; off <<= 1) {
        float o1 = __shfl_xor(m1, off);
        float o2 = __shfl_xor(m2, off);
        float M1 = fmaxf(m1, o1);
        float M2 = fmaxf(fminf(m1, o1), (m1 >= o1) ? m2 : o2);
        m1 = M1; m2 = M2;
    }
    const float gscore = m1 + m2;   // uniform within the 8-lane group

    // ---- keep top-LG groups (tie: lower group index wins, as in lax.top_k) ----
    const int g = lane >> 3;
    int cnt = 0;
    #pragma unroll
    for (int j = 0; j < G_GRP; j++) {
        float gj = __shfl(gscore, j * 8);
        cnt += (gj > gscore || (gj == gscore && j < g)) ? 1 : 0;
    }
    const bool keep = (cnt < LG_GRP);

    float smask[4];
    smask[0] = keep ? s[0] : -INFINITY;
    smask[1] = keep ? s[1] : -INFINITY;
    smask[2] = keep ? s[2] : -INFINITY;
    smask[3] = keep ? s[3] : -INFINITY;

    // ---- iteratively extract top-K experts (argmax butterfly, tie->lower idx) ----
    float wsum = 0.0f;
    float my_o = 0.0f;
    int   my_i = 0;

    #pragma unroll
    for (int k = 0; k < K_SEL; k++) {
        float bv = smask[0]; float bo = orig[0]; int bs = 0;
        if (smask[1] > bv) { bv = smask[1]; bo = orig[1]; bs = 1; }
        if (smask[2] > bv) { bv = smask[2]; bo = orig[2]; bs = 2; }
        if (smask[3] > bv) { bv = smask[3]; bo = orig[3]; bs = 3; }
        int bidx = lane * 4 + bs;

        #pragma unroll
        for (int off = 32; off >= 1; off >>= 1) {
            float ov = __shfl_xor(bv, off);
            float oo = __shfl_xor(bo, off);
            int   oi = __shfl_xor(bidx, off);
            if (ov > bv || (ov == bv && oi < bidx)) { bv = ov; bo = oo; bidx = oi; }
        }
        // all lanes now agree on the k-th winner
        wsum += bo;
        if (lane == k) { my_o = bo; my_i = bidx; }
        if ((bidx >> 2) == lane) {
            const int sl = bidx & 3;
            smask[0] = (sl == 0) ? -INFINITY : smask[0];
            smask[1] = (sl == 1) ? -INFINITY : smask[1];
            smask[2] = (sl == 2) ? -INFINITY : smask[2];
            smask[3] = (sl == 3) ? -INFINITY : smask[3];
        }
    }

    if (lane < K_SEL) {
        const float w = my_o * ROUTE_SCALE / wsum;
        out_w[(size_t)t * K_SEL + lane] = w;
        out_i[(size_t)t * K_SEL + lane] = (float)my_i;
        atomicAdd(&out_c[my_i], 1.0f);
    }
}

// ---------------- launch ----------------
extern "C" void kernel_launch(void* const* d_in, const int* in_sizes, int n_in,
                              void* d_out, int out_size, void* d_ws, size_t ws_size,
                              hipStream_t stream) {
    const float* x    = (const float*)d_in[0];
    const float* W    = (const float*)d_in[1];
    const float* bias = (const float*)d_in[2];

    float* out   = (float*)d_out;
    float* out_w = out;                                   // T*K
    float* out_i = out + (size_t)T_TOK * K_SEL;           // T*K
    float* out_c = out + (size_t)2 * T_TOK * K_SEL;       // E

    float* logits = (float*)d_ws;                         // T*E fp32 = 8 MB

    hipLaunchKernelGGL(gemm_logits_kernel,
                       dim3((T_TOK / BM) * (E_EXP / BN)), dim3(256), 0, stream,
                       x, W, logits);
    hipLaunchKernelGGL(zero_counts_kernel, dim3(1), dim3(E_EXP), 0, stream, out_c);
    hipLaunchKernelGGL(routing_kernel, dim3(T_TOK / 4), dim3(256), 0, stream,
                       logits, bias, out_w, out_i, out_c);
}

// Round 2
// 522.060 us; speedup vs baseline: 1.7573x; 1.7573x over previous
//
#include <hip/hip_runtime.h>
#include <math.h>

// Problem constants
#define T_TOK 8192
#define D_DIM 7168
#define E_EXP 256
#define K_SEL 8
#define G_GRP 8
#define LG_GRP 4
#define ROUTE_SCALE 2.5f

// GEMM tiling
#define BM 64
#define BN 128
#define BK 64
#define NKT (D_DIM / BK)       // 112
#define SCALE_LO 2048.0f       // 2^11
#define INV_SCALE (1.0f / 2048.0f)

typedef _Float16 half_t;
typedef _Float16 half8 __attribute__((ext_vector_type(8)));
typedef float f32x4 __attribute__((ext_vector_type(4)));

// ---------------------------------------------------------------------------
// logits[T,E] = x[T,D] @ W[E,D]^T  via 3-pass split-fp16 MFMA:
//   x = x_hi + x_lo*2^-11 ;  W = w_hi + w_lo*2^-11  (hi,lo fp16; lo scaled)
//   logit = x_hi*w_hi + 2^-11 * (x_hi*w_lo_s + x_lo_s*w_hi)   [drop lo*lo]
// Block: 64 tokens x 128 experts, 256 threads (4 waves, wave-tile 32x64).
// Grid: 128 m-tiles x 2 n-tiles = 256 blocks = 1/CU.
// LDS stores fp16 tiles in MFMA-fragment order (lane-contiguous 16B slots),
// XOR-swizzled (slot = (m+16q)^k8) so both the staging ds_write_b128 and the
// fragment ds_read_b128 are bank-conflict-free.
// ---------------------------------------------------------------------------
__global__ __launch_bounds__(256, 1)
void gemm_logits_f16split(const float* __restrict__ x,
                          const float* __restrict__ W,
                          float* __restrict__ logits) {
    // A: 4 panels(16 rows) x 2 kslices x 64 slots x 8 halfs = 8 KB each
    // B: 8 panels x 2 x 64 x 8 = 16 KB each. Total 48 KB.
    __shared__ __align__(16) half_t Ah[4 * 2 * 64 * 8];
    __shared__ __align__(16) half_t Al[4 * 2 * 64 * 8];
    __shared__ __align__(16) half_t Bh[8 * 2 * 64 * 8];
    __shared__ __align__(16) half_t Bl[8 * 2 * 64 * 8];

    const int tid = threadIdx.x;
    const int bid = blockIdx.x;
    // XCD swizzle: the two n-blocks of one m-tile land on the same XCD
    // (bid and bid+8 -> same bid%8), so x rows are fetched once per XCD L2.
    const int m_blk = (bid & 7) | ((bid >> 4) << 3);
    const int n_blk = (bid >> 3) & 1;
    const int row0 = m_blk * BM;
    const int col0 = n_blk * BN;

    const float* __restrict__ xA = x + (size_t)row0 * D_DIM;
    const float* __restrict__ wB = W + (size_t)col0 * D_DIM;

    // register prefetch buffers for the next K-tile (fp32)
    float4 pa[2][2], pb[4][2];

    auto load_tile = [&](int kt) {
        const int kbase = kt * BK;
        #pragma unroll
        for (int i = 0; i < 2; i++) {
            const int u = i * 256 + tid;       // 0..511
            const int r = u >> 3, k8 = u & 7;  // row 0..63, k-oct 0..7
            const float* p = xA + (size_t)r * D_DIM + kbase + k8 * 8;
            pa[i][0] = *(const float4*)p;
            pa[i][1] = *(const float4*)(p + 4);
        }
        #pragma unroll
        for (int i = 0; i < 4; i++) {
            const int u = i * 256 + tid;       // 0..1023
            const int r = u >> 3, k8 = u & 7;  // row 0..127
            const float* p = wB + (size_t)r * D_DIM + kbase + k8 * 8;
            pb[i][0] = *(const float4*)p;
            pb[i][1] = *(const float4*)(p + 4);
        }
    };

    auto cvt_store = [&](half_t* __restrict__ Hh, half_t* __restrict__ Hl,
                         const float4& v0, const float4& v1, int panel, int m, int k8) {
        float f[8] = {v0.x, v0.y, v0.z, v0.w, v1.x, v1.y, v1.z, v1.w};
        half8 hi, lo;
        #pragma unroll
        for (int j = 0; j < 8; j++) {
            const half_t h = (half_t)f[j];
            hi[j] = h;
            lo[j] = (half_t)((f[j] - (float)h) * SCALE_LO);
        }
        const int slot = (m + 16 * (k8 & 3)) ^ k8;               // XOR swizzle
        const int off = ((panel * 2 + (k8 >> 2)) * 64 + slot) * 8;
        *(half8*)&Hh[off] = hi;
        *(half8*)&Hl[off] = lo;
    };

    auto stage = [&]() {
        #pragma unroll
        for (int i = 0; i < 2; i++) {
            const int u = i * 256 + tid;
            const int r = u >> 3, k8 = u & 7;
            cvt_store(Ah, Al, pa[i][0], pa[i][1], r >> 4, r & 15, k8);
        }
        #pragma unroll
        for (int i = 0; i < 4; i++) {
            const int u = i * 256 + tid;
            const int r = u >> 3, k8 = u & 7;
            cvt_store(Bh, Bl, pb[i][0], pb[i][1], r >> 4, r & 15, k8);
        }
    };

    const int wave = tid >> 6, lane = tid & 63;
    const int q = lane >> 4;                  // 0..3
    const int mp0 = (wave >> 1) * 2;          // first of 2 m-panels
    const int np0 = (wave & 1) * 4;           // first of 4 n-panels

    f32x4 am[2][4] = {}, aca[2][4] = {}, acb[2][4] = {};

    auto compute = [&]() {
        #pragma unroll
        for (int ks = 0; ks < 2; ks++) {
            const int slot = lane ^ ((ks << 2) | q);
            half8 ah[2], al[2], bh[4], bl[4];
            #pragma unroll
            for (int mi = 0; mi < 2; mi++) {
                const int off = (((mp0 + mi) * 2 + ks) * 64 + slot) * 8;
                ah[mi] = *(const half8*)&Ah[off];
                al[mi] = *(const half8*)&Al[off];
            }
            #pragma unroll
            for (int ni = 0; ni < 4; ni++) {
                const int off = (((np0 + ni) * 2 + ks) * 64 + slot) * 8;
                bh[ni] = *(const half8*)&Bh[off];
                bl[ni] = *(const half8*)&Bl[off];
            }
            #pragma unroll
            for (int mi = 0; mi < 2; mi++)
                #pragma unroll
                for (int ni = 0; ni < 4; ni++) {
                    am[mi][ni]  = __builtin_amdgcn_mfma_f32_16x16x32_f16(ah[mi], bh[ni], am[mi][ni], 0, 0, 0);
                    aca[mi][ni] = __builtin_amdgcn_mfma_f32_16x16x32_f16(ah[mi], bl[ni], aca[mi][ni], 0, 0, 0);
                    acb[mi][ni] = __builtin_amdgcn_mfma_f32_16x16x32_f16(al[mi], bh[ni], acb[mi][ni], 0, 0, 0);
                }
        }
    };

    load_tile(0);
    #pragma unroll 1
    for (int kt = 0; kt < NKT; kt++) {
        __syncthreads();            // previous compute done; LDS free
        stage();                    // (waits vmcnt internally via compiler)
        __syncthreads();
        if (kt + 1 < NKT) load_tile(kt + 1);  // global prefetch overlaps MFMA
        compute();
    }

    // epilogue: C/D layout col=lane&15, row=q*4+reg
    #pragma unroll
    for (int mi = 0; mi < 2; mi++)
        #pragma unroll
        for (int ni = 0; ni < 4; ni++) {
            const f32x4 vm = am[mi][ni];
            const f32x4 vc = aca[mi][ni] + acb[mi][ni];
            const int ex = col0 + (np0 + ni) * 16 + (lane & 15);
            #pragma unroll
            for (int r = 0; r < 4; r++) {
                const int tok = row0 + (mp0 + mi) * 16 + q * 4 + r;
                logits[(size_t)tok * E_EXP + ex] = vm[r] + vc[r] * INV_SCALE;
            }
        }
}

// ---------------- zero the counts region of d_out ----------------
__global__ void zero_counts_kernel(float* __restrict__ c) {
    c[threadIdx.x] = 0.0f;
}

// ---------------- routing: one wave (64 lanes) per token ----------------
__global__ __launch_bounds__(256)
void routing_kernel(const float* __restrict__ logits,
                    const float* __restrict__ bias,
                    float* __restrict__ out_w,
                    float* __restrict__ out_i,
                    float* __restrict__ out_c) {
    const int wave = threadIdx.x >> 6;
    const int lane = threadIdx.x & 63;
    const int t    = blockIdx.x * 4 + wave;

    const float4 lg = *(const float4*)(logits + (size_t)t * E_EXP + lane * 4);
    const float4 bi = *(const float4*)(bias + lane * 4);

    float orig[4], s[4];
    orig[0] = 1.0f / (1.0f + expf(-lg.x));
    orig[1] = 1.0f / (1.0f + expf(-lg.y));
    orig[2] = 1.0f / (1.0f + expf(-lg.z));
    orig[3] = 1.0f / (1.0f + expf(-lg.w));
    s[0] = orig[0] + bi.x;
    s[1] = orig[1] + bi.y;
    s[2] = orig[2] + bi.z;
    s[3] = orig[3] + bi.w;

    float p1 = fmaxf(s[0], s[1]), p2 = fminf(s[0], s[1]);
    float q1 = fmaxf(s[2], s[3]), q2 = fminf(s[2], s[3]);
    float m1 = fmaxf(p1, q1);
    float m2 = fmaxf(fminf(p1, q1), (p1 >= q1) ? p2 : q2);

    #pragma unroll
    for (int off = 1; off <= 4; off <<= 1) {
        float o1 = __shfl_xor(m1, off);
        float o2 = __shfl_xor(m2, off);
        float M1 = fmaxf(m1, o1);
        float M2 = fmaxf(fminf(m1, o1), (m1 >= o1) ? m2 : o2);
        m1 = M1; m2 = M2;
    }
    const float gscore = m1 + m2;

    const int g = lane >> 3;
    int cnt = 0;
    #pragma unroll
    for (int j = 0; j < G_GRP; j++) {
        float gj = __shfl(gscore, j * 8);
        cnt += (gj > gscore || (gj == gscore && j < g)) ? 1 : 0;
    }
    const bool keep = (cnt < LG_GRP);

    float smask[4];
    smask[0] = keep ? s[0] : -INFINITY;
    smask[1] = keep ? s[1] : -INFINITY;
    smask[2] = keep ? s[2] : -INFINITY;
    smask[3] = keep ? s[3] : -INFINITY;

    float wsum = 0.0f;
    float my_o = 0.0f;
    int   my_i = 0;

    #pragma unroll
    for (int k = 0; k < K_SEL; k++) {
        float bv = smask[0]; float bo = orig[0]; int bs = 0;
        if (smask[1] > bv) { bv = smask[1]; bo = orig[1]; bs = 1; }
        if (smask[2] > bv) { bv = smask[2]; bo = orig[2]; bs = 2; }
        if (smask[3] > bv) { bv = smask[3]; bo = orig[3]; bs = 3; }
        int bidx = lane * 4 + bs;

        #pragma unroll
        for (int off = 32; off >= 1; off >>= 1) {
            float ov = __shfl_xor(bv, off);
            float oo = __shfl_xor(bo, off);
            int   oi = __shfl_xor(bidx, off);
            if (ov > bv || (ov == bv && oi < bidx)) { bv = ov; bo = oo; bidx = oi; }
        }
        wsum += bo;
        if (lane == k) { my_o = bo; my_i = bidx; }
        if ((bidx >> 2) == lane) {
            const int sl = bidx & 3;
            smask[0] = (sl == 0) ? -INFINITY : smask[0];
            smask[1] = (sl == 1) ? -INFINITY : smask[1];
            smask[2] = (sl == 2) ? -INFINITY : smask[2];
            smask[3] = (sl == 3) ? -INFINITY : smask[3];
        }
    }

    if (lane < K_SEL) {
        const float w = my_o * ROUTE_SCALE / wsum;
        out_w[(size_t)t * K_SEL + lane] = w;
        out_i[(size_t)t * K_SEL + lane] = (float)my_i;
        atomicAdd(&out_c[my_i], 1.0f);
    }
}

// ---------------- launch ----------------
extern "C" void kernel_launch(void* const* d_in, const int* in_sizes, int n_in,
                              void* d_out, int out_size, void* d_ws, size_t ws_size,
                              hipStream_t stream) {
    const float* x    = (const float*)d_in[0];
    const float* W    = (const float*)d_in[1];
    const float* bias = (const float*)d_in[2];

    float* out   = (float*)d_out;
    float* out_w = out;
    float* out_i = out + (size_t)T_TOK * K_SEL;
    float* out_c = out + (size_t)2 * T_TOK * K_SEL;

    float* logits = (float*)d_ws;   // 8 MB fp32

    hipLaunchKernelGGL(gemm_logits_f16split,
                       dim3((T_TOK / BM) * (E_EXP / BN)), dim3(256), 0, stream,
                       x, W, logits);
    hipLaunchKernelGGL(zero_counts_kernel, dim3(1), dim3(E_EXP), 0, stream, out_c);
    hipLaunchKernelGGL(routing_kernel, dim3(T_TOK / 4), dim3(256), 0, stream,
                       logits, bias, out_w, out_i, out_c);
}

// Round 3
// 394.319 us; speedup vs baseline: 2.3266x; 1.3240x over previous
//
#include <hip/hip_runtime.h>
#include <math.h>
#include <stdint.h>

// Problem constants
#define T_TOK 8192
#define D_DIM 7168
#define E_EXP 256
#define K_SEL 8
#define G_GRP 8
#define LG_GRP 4
#define ROUTE_SCALE 2.5f

// GEMM tiling
#define BM 64
#define BN 128
#define BK 64
#define NKT (D_DIM / BK)        // 112
#define KT_HALF (NKT / 2)       // 56 (split-K=2)
#define SCALE_LO 2048.0f        // 2^11
#define INV_SCALE (1.0f / 2048.0f)

typedef _Float16 half_t;
typedef _Float16 half8 __attribute__((ext_vector_type(8)));
typedef float f32x4 __attribute__((ext_vector_type(4)));

// Wf fragment-ordered halves: [h][nb][kt][p][ks][slot][8]
// offset(h,nb,kt,sl16,slot) = (((h*2+nb)*112 + kt)*16 + sl16)*512 + slot*8
#define WF_HALVES_PER_H (2 * 112 * 16 * 512)   // 1,835,008

__device__ __forceinline__ void load_lds16(const void* g, void* l) {
    __builtin_amdgcn_global_load_lds(
        (const __attribute__((address_space(1))) uint32_t*)g,
        (__attribute__((address_space(3))) uint32_t*)l, 16, 0, 0);
}

// ---------------------------------------------------------------------------
// Pre-pass: W[256][7168] fp32 -> Wf (f16 hi + scaled-lo residual), stored in
// MFMA-fragment tile order so GEMM B-staging is a pure global_load_lds copy.
// ---------------------------------------------------------------------------
__global__ __launch_bounds__(256)
void convert_W_kernel(const float* __restrict__ W, half_t* __restrict__ Wf) {
    const int u = blockIdx.x * 256 + threadIdx.x;   // 0..229375
    const int slot = u & 63;
    const int ks   = (u >> 6) & 1;
    const int p    = (u >> 7) & 7;
    const int t2   = u >> 10;          // 0..223
    const int kt   = t2 % 112;
    const int nb   = t2 / 112;
    const int e = nb * 128 + p * 16 + (slot & 15);
    const int k = kt * 64 + ks * 32 + (slot >> 4) * 8;

    const float* src = W + (size_t)e * D_DIM + k;
    float4 v0 = *(const float4*)src;
    float4 v1 = *(const float4*)(src + 4);
    float f[8] = {v0.x, v0.y, v0.z, v0.w, v1.x, v1.y, v1.z, v1.w};
    half8 hi, lo;
    #pragma unroll
    for (int j = 0; j < 8; j++) {
        const half_t h = (half_t)f[j];
        hi[j] = h;
        lo[j] = (half_t)((f[j] - (float)h) * SCALE_LO);
    }
    *(half8*)&Wf[(size_t)u * 8] = hi;
    *(half8*)&Wf[(size_t)WF_HALVES_PER_H + (size_t)u * 8] = lo;
}

// ---------------------------------------------------------------------------
// GEMM: partial logits via 3-term split-f16 MFMA, split-K=2.
// Block: 64 tok x 128 exp x half-K, 256 thr (4 waves, wave-tile 32x64).
// Grid 512 = 2 blocks/CU. A: fp32->regs->cvt->ds_write (XOR swizzle, round-2
// verified). B: global_load_lds from pre-converted Wf, double-buffered,
// prefetched during compute so the barrier vmcnt drain lands post-compute.
// ---------------------------------------------------------------------------
__global__ __launch_bounds__(256, 2)
void gemm_logits_f16split(const float* __restrict__ x,
                          const half_t* __restrict__ Wf,
                          float* __restrict__ plane0,
                          float* __restrict__ plane1) {
    __shared__ __align__(16) half_t Ah[4 * 2 * 64 * 8];   // 8 KB
    __shared__ __align__(16) half_t Al[4 * 2 * 64 * 8];   // 8 KB
    __shared__ __align__(16) half_t Bbuf[2][32][512];     // 64 KB (hi|lo x 16 slices)

    const int tid = threadIdx.x;
    const int bid = blockIdx.x;
    // nb fastest: the 4 blocks covering one m-row (2 nb x 2 split) are
    // temporally adjacent -> x rows stream from HBM ~once.
    const int nb    = bid & 1;
    const int split = (bid >> 1) & 1;
    const int m_blk = bid >> 2;
    const int row0 = m_blk * BM;
    const int ks0  = split * KT_HALF;

    const float* __restrict__ xA = x + (size_t)row0 * D_DIM;
    float* __restrict__ plane = split ? plane1 : plane0;

    const int wave = tid >> 6, lane = tid & 63;
    const int q = lane >> 4;
    const int mp0 = (wave >> 1) * 2;
    const int np0 = (wave & 1) * 4;

    float4 pa[2][2];

    auto load_A = [&](int kt) {
        const int kbase = kt * BK;
        #pragma unroll
        for (int i = 0; i < 2; i++) {
            const int u = i * 256 + tid;
            const int r = u >> 3, k8 = u & 7;
            const float* p = xA + (size_t)r * D_DIM + kbase + k8 * 8;
            pa[i][0] = *(const float4*)p;
            pa[i][1] = *(const float4*)(p + 4);
        }
    };

    auto stage_A = [&]() {
        #pragma unroll
        for (int i = 0; i < 2; i++) {
            const int u = i * 256 + tid;
            const int r = u >> 3, k8 = u & 7;
            float f[8] = {pa[i][0].x, pa[i][0].y, pa[i][0].z, pa[i][0].w,
                          pa[i][1].x, pa[i][1].y, pa[i][1].z, pa[i][1].w};
            half8 hi, lo;
            #pragma unroll
            for (int j = 0; j < 8; j++) {
                const half_t h = (half_t)f[j];
                hi[j] = h;
                lo[j] = (half_t)((f[j] - (float)h) * SCALE_LO);
            }
            const int m = r & 15, qq = k8 & 3, kss = k8 >> 2;
            const int slot = (m + 16 * qq) ^ k8;
            const int off = (((r >> 4) * 2 + kss) * 64 + slot) * 8;
            *(half8*)&Ah[off] = hi;
            *(half8*)&Al[off] = lo;
        }
    };

    auto issue_B = [&](int tt) {
        const int kt = ks0 + tt;
        half_t* bb = &Bbuf[tt & 1][0][0];
        #pragma unroll
        for (int i = 0; i < 8; i++) {
            const int s32 = i * 4 + wave;           // 0..31
            const int h = s32 >> 4, sl = s32 & 15;
            const half_t* src = Wf +
                ((size_t)((h * 2 + nb) * 112 + kt) * 16 + sl) * 512 + lane * 8;
            load_lds16(src, bb + s32 * 512);
        }
    };

    f32x4 ach[2][4] = {}, acc[2][4] = {};

    auto compute = [&](int tt) {
        const half_t* bb = &Bbuf[tt & 1][0][0];
        #pragma unroll
        for (int ks = 0; ks < 2; ks++) {
            const int slot = lane ^ ((ks << 2) | q);
            half8 ah[2], al[2], bh[4], bl[4];
            #pragma unroll
            for (int mi = 0; mi < 2; mi++) {
                const int off = (((mp0 + mi) * 2 + ks) * 64 + slot) * 8;
                ah[mi] = *(const half8*)&Ah[off];
                al[mi] = *(const half8*)&Al[off];
            }
            #pragma unroll
            for (int ni = 0; ni < 4; ni++) {
                const int s32 = (np0 + ni) * 2 + ks;
                bh[ni] = *(const half8*)&bb[s32 * 512 + lane * 8];
                bl[ni] = *(const half8*)&bb[(16 + s32) * 512 + lane * 8];
            }
            #pragma unroll
            for (int mi = 0; mi < 2; mi++)
                #pragma unroll
                for (int ni = 0; ni < 4; ni++) {
                    ach[mi][ni] = __builtin_amdgcn_mfma_f32_16x16x32_f16(ah[mi], bh[ni], ach[mi][ni], 0, 0, 0);
                    acc[mi][ni] = __builtin_amdgcn_mfma_f32_16x16x32_f16(ah[mi], bl[ni], acc[mi][ni], 0, 0, 0);
                    acc[mi][ni] = __builtin_amdgcn_mfma_f32_16x16x32_f16(al[mi], bh[ni], acc[mi][ni], 0, 0, 0);
                }
        }
    };

    issue_B(0);
    load_A(ks0);

    #pragma unroll 1
    for (int tt = 0; tt < KT_HALF; tt++) {
        __syncthreads();                 // drains B-lds(tt) + A-regs(tt)
        stage_A();
        __syncthreads();                 // A ds_writes visible; nothing global in flight
        if (tt + 1 < KT_HALF) {
            issue_B(tt + 1);             // lands during compute, drains next barrier
            load_A(ks0 + tt + 1);
        }
        compute(tt);
    }

    const int col0 = nb * BN;
    #pragma unroll
    for (int mi = 0; mi < 2; mi++)
        #pragma unroll
        for (int ni = 0; ni < 4; ni++) {
            const f32x4 vh = ach[mi][ni];
            const f32x4 vc = acc[mi][ni];
            const int ex = col0 + (np0 + ni) * 16 + (lane & 15);
            #pragma unroll
            for (int r = 0; r < 4; r++) {
                const int tok = row0 + (mp0 + mi) * 16 + q * 4 + r;
                plane[(size_t)tok * E_EXP + ex] = vh[r] + vc[r] * INV_SCALE;
            }
        }
}

// ---------------------------------------------------------------------------
// Routing: one wave per token. Reads both split-K planes. No atomics.
// ---------------------------------------------------------------------------
__global__ __launch_bounds__(256)
void routing_kernel(const float* __restrict__ plane0,
                    const float* __restrict__ plane1,
                    const float* __restrict__ bias,
                    float* __restrict__ out_w,
                    float* __restrict__ out_i) {
    const int wave = threadIdx.x >> 6;
    const int lane = threadIdx.x & 63;
    const int t    = blockIdx.x * 4 + wave;

    const float4 l0 = *(const float4*)(plane0 + (size_t)t * E_EXP + lane * 4);
    const float4 l1 = *(const float4*)(plane1 + (size_t)t * E_EXP + lane * 4);
    const float4 bi = *(const float4*)(bias + lane * 4);
    float lg[4] = {l0.x + l1.x, l0.y + l1.y, l0.z + l1.z, l0.w + l1.w};

    float orig[4], s[4];
    #pragma unroll
    for (int j = 0; j < 4; j++)
        orig[j] = 1.0f / (1.0f + expf(-lg[j]));
    s[0] = orig[0] + bi.x; s[1] = orig[1] + bi.y;
    s[2] = orig[2] + bi.z; s[3] = orig[3] + bi.w;

    float p1 = fmaxf(s[0], s[1]), p2 = fminf(s[0], s[1]);
    float q1 = fmaxf(s[2], s[3]), q2 = fminf(s[2], s[3]);
    float m1 = fmaxf(p1, q1);
    float m2 = fmaxf(fminf(p1, q1), (p1 >= q1) ? p2 : q2);

    #pragma unroll
    for (int off = 1; off <= 4; off <<= 1) {
        float o1 = __shfl_xor(m1, off);
        float o2 = __shfl_xor(m2, off);
        float M1 = fmaxf(m1, o1);
        float M2 = fmaxf(fminf(m1, o1), (m1 >= o1) ? m2 : o2);
        m1 = M1; m2 = M2;
    }
    const float gscore = m1 + m2;

    const int g = lane >> 3;
    int cnt = 0;
    #pragma unroll
    for (int j = 0; j < G_GRP; j++) {
        float gj = __shfl(gscore, j * 8);
        cnt += (gj > gscore || (gj == gscore && j < g)) ? 1 : 0;
    }
    const bool keep = (cnt < LG_GRP);

    float smask[4];
    #pragma unroll
    for (int j = 0; j < 4; j++) smask[j] = keep ? s[j] : -INFINITY;

    float wsum = 0.0f, my_o = 0.0f;
    int my_i = 0;

    #pragma unroll
    for (int k = 0; k < K_SEL; k++) {
        float bv = smask[0]; float bo = orig[0]; int bs = 0;
        if (smask[1] > bv) { bv = smask[1]; bo = orig[1]; bs = 1; }
        if (smask[2] > bv) { bv = smask[2]; bo = orig[2]; bs = 2; }
        if (smask[3] > bv) { bv = smask[3]; bo = orig[3]; bs = 3; }
        int bidx = lane * 4 + bs;

        #pragma unroll
        for (int off = 32; off >= 1; off >>= 1) {
            float ov = __shfl_xor(bv, off);
            float oo = __shfl_xor(bo, off);
            int   oi = __shfl_xor(bidx, off);
            if (ov > bv || (ov == bv && oi < bidx)) { bv = ov; bo = oo; bidx = oi; }
        }
        wsum += bo;
        if (lane == k) { my_o = bo; my_i = bidx; }
        if ((bidx >> 2) == lane) {
            const int sl = bidx & 3;
            smask[0] = (sl == 0) ? -INFINITY : smask[0];
            smask[1] = (sl == 1) ? -INFINITY : smask[1];
            smask[2] = (sl == 2) ? -INFINITY : smask[2];
            smask[3] = (sl == 3) ? -INFINITY : smask[3];
        }
    }

    if (lane < K_SEL) {
        out_w[(size_t)t * K_SEL + lane] = my_o * ROUTE_SCALE / wsum;
        out_i[(size_t)t * K_SEL + lane] = (float)my_i;
    }
}

// ---------------------------------------------------------------------------
// Counts: block e scans all T*K indices for expert e. L2-hot, zero atomics.
// ---------------------------------------------------------------------------
__global__ __launch_bounds__(256)
void count_kernel(const float* __restrict__ idxf, float* __restrict__ out_c) {
    const float fe = (float)blockIdx.x;
    int c = 0;
    const float4* p = (const float4*)idxf;          // T*K/4 = 16384
    for (int i = threadIdx.x; i < (T_TOK * K_SEL / 4); i += 256) {
        float4 v = p[i];
        c += (v.x == fe) + (v.y == fe) + (v.z == fe) + (v.w == fe);
    }
    __shared__ int red[4];
    #pragma unroll
    for (int off = 32; off >= 1; off >>= 1) c += __shfl_down(c, off);
    if ((threadIdx.x & 63) == 0) red[threadIdx.x >> 6] = c;
    __syncthreads();
    if (threadIdx.x == 0)
        out_c[blockIdx.x] = (float)(red[0] + red[1] + red[2] + red[3]);
}

// ---------------- launch ----------------
extern "C" void kernel_launch(void* const* d_in, const int* in_sizes, int n_in,
                              void* d_out, int out_size, void* d_ws, size_t ws_size,
                              hipStream_t stream) {
    const float* x    = (const float*)d_in[0];
    const float* W    = (const float*)d_in[1];
    const float* bias = (const float*)d_in[2];

    float* out   = (float*)d_out;
    float* out_w = out;
    float* out_i = out + (size_t)T_TOK * K_SEL;
    float* out_c = out + (size_t)2 * T_TOK * K_SEL;

    float* plane0 = (float*)d_ws;                          // 8 MB
    float* plane1 = plane0 + (size_t)T_TOK * E_EXP;        // 8 MB
    half_t* Wf    = (half_t*)(plane1 + (size_t)T_TOK * E_EXP);  // 7.34 MB

    hipLaunchKernelGGL(convert_W_kernel, dim3(896), dim3(256), 0, stream, W, Wf);
    hipLaunchKernelGGL(gemm_logits_f16split, dim3(512), dim3(256), 0, stream,
                       x, Wf, plane0, plane1);
    hipLaunchKernelGGL(routing_kernel, dim3(T_TOK / 4), dim3(256), 0, stream,
                       plane0, plane1, bias, out_w, out_i);
    hipLaunchKernelGGL(count_kernel, dim3(E_EXP), dim3(256), 0, stream,
                       out_i, out_c);
}